// Round 3
// baseline (38.562 us; speedup 1.0000x reference)
//
#include <hip/hip_runtime.h>

__device__ __forceinline__ float rsq(float x)  { return __builtin_amdgcn_rsqf(x); }
__device__ __forceinline__ float fsqrt(float x){ return __builtin_amdgcn_sqrtf(x); }

__device__ __forceinline__ float row_loss(float4 p, float4 g, int lab)
{
    // quat layout per row: [w, x, y, z]
    float pw = p.x, px = p.y, py = p.z, pz = p.w;
    float gw = g.x, gx = g.y, gy = g.z, gz = g.w;

    float np2 = pw*pw + px*px + py*py + pz*pz;
    float ng2 = gw*gw + gx*gx + gy*gy + gz*gz;

    // geodesic dots without normalizing: |p.g| * rsqrt(|p|^2 |g|^2)
    float d1 = fabsf(pw*gw + px*gx + py*gy + pz*gz);
    // q_gt * (0,0,0,1) = (-z, y, -x, w)
    float d2 = fabsf(-pw*gz + px*gy - py*gx + pz*gw);

    bool is_axial = (lab == 5)  | (lab == 11);
    bool is_disc  = (lab == 10) | (lab == 12);

    // acos monotone decreasing -> min angle = acos of max dot
    float dmax = is_disc ? fmaxf(d1, d2) : d1;
    float d = dmax * rsq(np2 * ng2);
    d = fminf(d, 1.f - 1e-6f);

    // fast acos on [0,1]: acos(x) ~= sqrt(1-x) * poly(x), abs err ~6.8e-5
    float poly = 1.5707288f + d*(-0.2121144f + d*(0.0742610f + d*(-0.0187293f)));
    float loss_geo = 2.f * fsqrt(1.f - d) * poly;

    // rotate_z on UNNORMALIZED quats: u = |q|^2 * z_rot, same direction.
    float upx = 2.f*(pw*py + px*pz);
    float upy = 2.f*(py*pz - pw*px);
    float upz = np2 - 2.f*(px*px + py*py);
    float ugx = 2.f*(gw*gy + gx*gz);
    float ugy = 2.f*(gy*gz - gw*gx);
    float ugz = ng2 - 2.f*(gx*gx + gy*gy);

    float dotz = upx*ugx + upy*ugy + upz*ugz;
    float rzz  = rsq((upx*upx + upy*upy + upz*upz) *
                     (ugx*ugx + ugy*ugy + ugz*ugz));
    float loss_axial = 1.f - dotz * rzz;

    return is_axial ? loss_axial : loss_geo;
}

#define BATCH 8

// Per-block partial sums of the per-row loss. Structure: issue ALL of a
// BATCH's 24 vmem loads back-to-back (explicit arrays -> compiler batches
// them before the first waitcnt), then compute. 8x the per-wave MLP of the
// plain grid-stride loop (which left VGPR=16..36 and exposed full load
// latency every iteration).
__global__ __launch_bounds__(256) void geo_loss_partial(
    const float4* __restrict__ qp4, const float4* __restrict__ qg4,
    const int* __restrict__ labels, float* __restrict__ partial, int B)
{
    int tid = blockIdx.x * blockDim.x + threadIdx.x;
    int stride = gridDim.x * blockDim.x;
    float acc = 0.f;

    int i = tid;
    for (; i + (BATCH - 1) * stride < B; i += BATCH * stride) {
        float4 P[BATCH], G[BATCH];
        int L[BATCH];
        #pragma unroll
        for (int u = 0; u < BATCH; ++u) P[u] = qp4[i + u * stride];
        #pragma unroll
        for (int u = 0; u < BATCH; ++u) G[u] = qg4[i + u * stride];
        #pragma unroll
        for (int u = 0; u < BATCH; ++u) L[u] = labels[i + u * stride];
        #pragma unroll
        for (int u = 0; u < BATCH; ++u) acc += row_loss(P[u], G[u], L[u]);
    }
    for (; i < B; i += stride)
        acc += row_loss(qp4[i], qg4[i], labels[i]);

    // wave (64-lane) reduce
    #pragma unroll
    for (int off = 32; off > 0; off >>= 1)
        acc += __shfl_down(acc, off);

    __shared__ float sdata[4];  // 256 threads / 64 lanes = 4 waves
    int lane = threadIdx.x & 63;
    int wid  = threadIdx.x >> 6;
    if (lane == 0) sdata[wid] = acc;
    __syncthreads();
    if (threadIdx.x == 0)
        partial[blockIdx.x] = sdata[0] + sdata[1] + sdata[2] + sdata[3];
}

__global__ __launch_bounds__(256) void geo_loss_finalize(
    const float* __restrict__ partial, int n, float* __restrict__ out, int B)
{
    __shared__ double sd[256];
    double a = 0.0;
    for (int i = threadIdx.x; i < n; i += 256)
        a += (double)partial[i];
    sd[threadIdx.x] = a;
    __syncthreads();
    for (int s = 128; s > 0; s >>= 1) {
        if (threadIdx.x < s) sd[threadIdx.x] += sd[threadIdx.x + s];
        __syncthreads();
    }
    if (threadIdx.x == 0)
        out[0] = (float)(sd[0] / (double)B);
}

extern "C" void kernel_launch(void* const* d_in, const int* in_sizes, int n_in,
                              void* d_out, int out_size, void* d_ws, size_t ws_size,
                              hipStream_t stream) {
    int B = in_sizes[0] / 4;
    const float4* qp = (const float4*)d_in[0];
    const float4* qg = (const float4*)d_in[1];
    const int* labels = (const int*)d_in[2];
    float* out = (float*)d_out;
    float* partial = (float*)d_ws;

    int blocks = 2048;
    if (ws_size < (size_t)blocks * sizeof(float))
        blocks = (int)(ws_size / sizeof(float));  // defensive; ws is normally MBs

    geo_loss_partial<<<blocks, 256, 0, stream>>>(qp, qg, labels, partial, B);
    geo_loss_finalize<<<1, 256, 0, stream>>>(partial, blocks, out, B);
}

// Round 5
// 33.554 us; speedup vs baseline: 1.1492x; 1.1492x over previous
//
#include <hip/hip_runtime.h>

// Native clang vector type: __builtin_nontemporal_load requires a pointer to
// scalar/vector-of-scalar, not HIP_vector_type.
typedef float floatx4 __attribute__((ext_vector_type(4)));

__device__ __forceinline__ float rsq(float x)  { return __builtin_amdgcn_rsqf(x); }
__device__ __forceinline__ float fsqrt(float x){ return __builtin_amdgcn_sqrtf(x); }

__device__ __forceinline__ float row_loss(floatx4 p, floatx4 g, int lab)
{
    // quat layout per row: [w, x, y, z]
    float pw = p.x, px = p.y, py = p.z, pz = p.w;
    float gw = g.x, gx = g.y, gy = g.z, gz = g.w;

    float np2 = pw*pw + px*px + py*py + pz*pz;
    float ng2 = gw*gw + gx*gx + gy*gy + gz*gz;

    // geodesic dots without normalizing: |p.g| * rsqrt(|p|^2 |g|^2)
    float d1 = fabsf(pw*gw + px*gx + py*gy + pz*gz);
    // q_gt * (0,0,0,1) = (-z, y, -x, w)
    float d2 = fabsf(-pw*gz + px*gy - py*gx + pz*gw);

    bool is_axial = (lab == 5)  | (lab == 11);
    bool is_disc  = (lab == 10) | (lab == 12);

    // acos monotone decreasing -> min angle = acos of max dot
    float dmax = is_disc ? fmaxf(d1, d2) : d1;
    float d = dmax * rsq(np2 * ng2);
    d = fminf(d, 1.f - 1e-6f);

    // fast acos on [0,1]: acos(x) ~= sqrt(1-x) * poly(x), abs err ~6.8e-5
    float poly = 1.5707288f + d*(-0.2121144f + d*(0.0742610f + d*(-0.0187293f)));
    float loss_geo = 2.f * fsqrt(1.f - d) * poly;

    // rotate_z on UNNORMALIZED quats: u = |q|^2 * z_rot, same direction.
    float upx = 2.f*(pw*py + px*pz);
    float upy = 2.f*(py*pz - pw*px);
    float upz = np2 - 2.f*(px*px + py*py);
    float ugx = 2.f*(gw*gy + gx*gz);
    float ugy = 2.f*(gy*gz - gw*gx);
    float ugz = ng2 - 2.f*(gx*gx + gy*gy);

    float dotz = upx*ugx + upy*ugy + upz*ugz;
    float rzz  = rsq((upx*upx + upy*upy + upz*upz) *
                     (ugx*ugx + ugy*ugy + ugz*ugz));
    float loss_axial = 1.f - dotz * rzz;

    return is_axial ? loss_axial : loss_geo;
}

// Per-block partial sums. Nontemporal loads: the 151 MB working set is
// re-streamed every replay with zero intra-dispatch reuse; marking the
// streams evict-first probes whether the cache-hit service path (not HBM)
// is the ~2.8 TB/s delivery ceiling seen in R1-R3.
__global__ __launch_bounds__(256) void geo_loss_partial(
    const floatx4* __restrict__ qp4, const floatx4* __restrict__ qg4,
    const int* __restrict__ labels, float* __restrict__ partial, int B)
{
    int tid = blockIdx.x * blockDim.x + threadIdx.x;
    int stride = gridDim.x * blockDim.x;
    float acc = 0.f;

    #pragma unroll 4
    for (int i = tid; i < B; i += stride) {
        floatx4 p = __builtin_nontemporal_load(&qp4[i]);
        floatx4 g = __builtin_nontemporal_load(&qg4[i]);
        int lab  = __builtin_nontemporal_load(&labels[i]);
        acc += row_loss(p, g, lab);
    }

    // wave (64-lane) reduce
    #pragma unroll
    for (int off = 32; off > 0; off >>= 1)
        acc += __shfl_down(acc, off);

    __shared__ float sdata[4];  // 256 threads / 64 lanes = 4 waves
    int lane = threadIdx.x & 63;
    int wid  = threadIdx.x >> 6;
    if (lane == 0) sdata[wid] = acc;
    __syncthreads();
    if (threadIdx.x == 0)
        partial[blockIdx.x] = sdata[0] + sdata[1] + sdata[2] + sdata[3];
}

__global__ __launch_bounds__(256) void geo_loss_finalize(
    const float* __restrict__ partial, int n, float* __restrict__ out, int B)
{
    __shared__ double sd[256];
    double a = 0.0;
    for (int i = threadIdx.x; i < n; i += 256)
        a += (double)partial[i];
    sd[threadIdx.x] = a;
    __syncthreads();
    for (int s = 128; s > 0; s >>= 1) {
        if (threadIdx.x < s) sd[threadIdx.x] += sd[threadIdx.x + s];
        __syncthreads();
    }
    if (threadIdx.x == 0)
        out[0] = (float)(sd[0] / (double)B);
}

extern "C" void kernel_launch(void* const* d_in, const int* in_sizes, int n_in,
                              void* d_out, int out_size, void* d_ws, size_t ws_size,
                              hipStream_t stream) {
    int B = in_sizes[0] / 4;
    const floatx4* qp = (const floatx4*)d_in[0];
    const floatx4* qg = (const floatx4*)d_in[1];
    const int* labels = (const int*)d_in[2];
    float* out = (float*)d_out;
    float* partial = (float*)d_ws;

    int blocks = 4096;  // 4 rows/thread; rules out dispatch-tail occupancy artifacts
    if (ws_size < (size_t)blocks * sizeof(float))
        blocks = (int)(ws_size / sizeof(float));

    geo_loss_partial<<<blocks, 256, 0, stream>>>(qp, qg, labels, partial, B);
    geo_loss_finalize<<<1, 256, 0, stream>>>(partial, blocks, out, B);
}